// Round 8
// baseline (476.487 us; speedup 1.0000x reference)
//
#include <hip/hip_runtime.h>
#include <math.h>

#define NEG_SLOPE 0.2f

typedef __attribute__((ext_vector_type(8))) short bf16x8;   // 8 bf16 (4 VGPRs)
typedef __attribute__((ext_vector_type(4))) short bf16x4;   // 4 bf16 (2 VGPRs)
typedef __attribute__((ext_vector_type(4))) float f32x4;    // MFMA acc
typedef __attribute__((ext_vector_type(2))) float f32x2;

__device__ __forceinline__ float b2f(short s) {
  return __uint_as_float(((unsigned int)(unsigned short)s) << 16);
}
__device__ __forceinline__ unsigned short f2b_rne(float f) {
  unsigned int u = __float_as_uint(f);
  u = (u + 0x7FFF + ((u >> 16) & 1)) >> 16;
  return (unsigned short)u;
}

// packed fp8-row accumulate: acc2[q] (channels 2q,2q+1) += a * fp8(raw), 8 channels
__device__ __forceinline__ void acc8_fp8(uint2 raw, float a, f32x2* acc2) {
  f32x2 w2; w2[0] = a; w2[1] = a;
  acc2[0] = __builtin_elementwise_fma(w2, __builtin_amdgcn_cvt_pk_f32_fp8((int)raw.x, false), acc2[0]);
  acc2[1] = __builtin_elementwise_fma(w2, __builtin_amdgcn_cvt_pk_f32_fp8((int)raw.x, true),  acc2[1]);
  acc2[2] = __builtin_elementwise_fma(w2, __builtin_amdgcn_cvt_pk_f32_fp8((int)raw.y, false), acc2[2]);
  acc2[3] = __builtin_elementwise_fma(w2, __builtin_amdgcn_cvt_pk_f32_fp8((int)raw.y, true),  acc2[3]);
}

// 4-channel variant (one dword of fp8)
__device__ __forceinline__ void acc4_fp8(unsigned int raw, float a, f32x2* acc2) {
  f32x2 w2; w2[0] = a; w2[1] = a;
  acc2[0] = __builtin_elementwise_fma(w2, __builtin_amdgcn_cvt_pk_f32_fp8((int)raw, false), acc2[0]);
  acc2[1] = __builtin_elementwise_fma(w2, __builtin_amdgcn_cvt_pk_f32_fp8((int)raw, true),  acc2[1]);
}

// async global->LDS, 16B per lane; LDS dest is wave-uniform base + lane*16
__device__ __forceinline__ void gload16(const unsigned short* g, unsigned short* l) {
  __builtin_amdgcn_global_load_lds(
      (const __attribute__((address_space(1))) unsigned int*)g,
      (__attribute__((address_space(3))) unsigned int*)l, 16, 0, 0);
}

template<int N> __device__ __forceinline__ void vmwait() {
  asm volatile("s_waitcnt vmcnt(%0)" :: "n"(N) : "memory");
}

// byte s of each of 4 dwords -> packed dword
__device__ __forceinline__ unsigned int bsel(uint4 d, int s) {
  return ((d.x >> (8 * s)) & 0xffu) | (((d.y >> (8 * s)) & 0xffu) << 8)
       | (((d.z >> (8 * s)) & 0xffu) << 16) | (((d.w >> (8 * s)) & 0xffu) << 24);
}

// ---------------- fused prep: cvt x, cvt fp, 4 weight transposes ----------------
__device__ __forceinline__ void tr_one(const float* __restrict__ W,
                                       unsigned short* __restrict__ WT,
                                       int K, int N, int idx)
{
  if (idx < K * N) {
    int k = idx / N, n = idx - k * N;
    WT[(size_t)n * K + k] = f2b_rne(W[idx]);
  }
}

__global__ __launch_bounds__(256) void prep_all(
    const float* __restrict__ x, unsigned short* __restrict__ xb, size_t nx, int B0,
    const float* __restrict__ fp, unsigned short* __restrict__ fpb, size_t nf, int B1,
    const float* __restrict__ W1, unsigned short* __restrict__ W1T,
    const float* __restrict__ W2, unsigned short* __restrict__ W2T,
    const float* __restrict__ Wfp, unsigned short* __restrict__ WfpT,
    const float* __restrict__ Wfc1, unsigned short* __restrict__ Wfc1T)
{
  int b = blockIdx.x;
  const int t = threadIdx.x;
  if (b < B0) {
    size_t i = (size_t)b * 256 + t;
    if (i < nx) xb[i] = f2b_rne(x[i]);
    return;
  }
  b -= B0;
  if (b < B1) {
    size_t i = (size_t)b * 256 + t;
    if (i < nf) fpb[i] = f2b_rne(fp[i]);
    return;
  }
  b -= B1;
  if (b < 128) { tr_one(W1, W1T, 128, 256, b * 256 + t); return; }
  b -= 128;
  if (b < 512) { tr_one(W2, W2T, 256, 512, b * 256 + t); return; }
  b -= 512;
  if (b < 512) { tr_one(Wfp, WfpT, 2048, 64, b * 256 + t); return; }
  b -= 512;
  tr_one(Wfc1, Wfc1T, 576, 64, b * 256 + t);
}

// ---------------- e-projection prep: BeT[ecol][k] = bf16( sum_c W[k][h*C+c]*a[h][c] ) ----
__global__ __launch_bounds__(256) void prep_e(
    const float* __restrict__ W1, const float* __restrict__ as1, const float* __restrict__ ad1,
    const float* __restrict__ W2, const float* __restrict__ as2, const float* __restrict__ ad2,
    unsigned short* __restrict__ BeT1, unsigned short* __restrict__ BeT2)
{
  const int b = blockIdx.x;
  const int k = threadIdx.x;
  if (b < 4) {                       // conv1: K=128, C=64, N=256
    if (k < 128) {
      float ss = 0.f, sd = 0.f;
      for (int c = 0; c < 64; ++c) {
        float w = W1[k * 256 + b * 64 + c];
        ss += w * as1[b * 64 + c];
        sd += w * ad1[b * 64 + c];
      }
      BeT1[b * 128 + k] = f2b_rne(ss);
      BeT1[(4 + b) * 128 + k] = f2b_rne(sd);
    }
  } else {                           // conv2: K=256, C=128, N=512
    const int h = b - 4;
    float ss = 0.f, sd = 0.f;
    for (int c = 0; c < 128; ++c) {
      float w = W2[k * 512 + h * 128 + c];
      ss += w * as2[h * 128 + c];
      sd += w * ad2[h * 128 + c];
    }
    BeT2[h * 256 + k] = f2b_rne(ss);
    BeT2[(4 + h) * 256 + k] = f2b_rne(sd);
  }
}

// ---------------- MFMA GEMM; C in fp8(e4m3); es/ed as extra MFMA columns ----------------
template<int KK>
__global__ __launch_bounds__(256) void gemm_mfma(
    const unsigned short* __restrict__ A, const unsigned short* __restrict__ BT,
    unsigned char* __restrict__ Cout, int M, int N,
    const unsigned short* __restrict__ BeT,
    float* __restrict__ es, float* __restrict__ ed, int nh)
{
  constexpr int NT = KK / 32;          // 4 (conv1) or 8 (conv2)
  constexpr int LDE = KK + 8;          // Be stride (2-way-free banking)
  __shared__ unsigned short As[4][128 * 32];   // 32 KB
  __shared__ unsigned short Bs[4][128 * 32];   // 32 KB
  __shared__ unsigned short Be[16 * LDE];      // ~8 KB
  const int tid  = threadIdx.x;
  const int wave = tid >> 6;
  const int lane = tid & 63;
  const int ln   = lane & 15;
  const int quad = lane >> 4;
  const int wr0  = (wave >> 1) * 64;
  const int wc0  = (wave & 1) * 64;

  // XCD-bijective chunked swizzle (m204), col-fastest within an XCD chunk.
  const int nwg = gridDim.x;
  const int ncol = N >> 7;
  const int bid = blockIdx.x;
  const int qq = nwg >> 3, rr = nwg & 7;
  const int xc = bid & 7, io = bid >> 3;
  const int swz = (xc < rr ? xc * (qq + 1) : rr * (qq + 1) + (xc - rr) * qq) + io;
  const int bn = (swz % ncol) * 128;
  const int bm = (swz / ncol) * 128;
  const bool do_e = (bn == 0) && (wc0 == 0);

  // stage Be once (bn==0 blocks only): 8 rows x KK elems
  if (bn == 0 && tid < KK) {
    const int rrw = tid / (KK / 8);
    const int ccl = (tid % (KK / 8)) * 8;
    bf16x8 v = *(const bf16x8*)(BeT + rrw * KK + ccl);
    *(bf16x8*)(&Be[rrw * LDE + ccl]) = v;
  }
  __syncthreads();

  // staging: wave w owns tile rows [32w,32w+32) as two 16-row segments.
  const int srow = lane >> 2;
  const int cch  = lane & 3;
  const int rt0  = wave * 32 + srow;
  const int ksw  = ((cch ^ (srow & 3)) << 3);
  int ar0 = bm + rt0;      if (ar0 >= M) ar0 = M - 1;   // clamp tail rows
  int ar1 = bm + rt0 + 16; if (ar1 >= M) ar1 = M - 1;
  const unsigned short* gA0 = A + (size_t)ar0 * KK + ksw;
  const unsigned short* gA1 = A + (size_t)ar1 * KK + ksw;
  const unsigned short* gB0 = BT + (size_t)(bn + rt0) * KK + ksw;
  const unsigned short* gB1 = BT + (size_t)(bn + rt0 + 16) * KK + ksw;

  auto stage = [&](int T) {
    const int b = T & 3;
    const int kk = T * 32;
    gload16(gA0 + kk, &As[b][(wave * 32) * 32]);
    gload16(gA1 + kk, &As[b][(wave * 32 + 16) * 32]);
    gload16(gB0 + kk, &Bs[b][(wave * 32) * 32]);
    gload16(gB1 + kk, &Bs[b][(wave * 32 + 16) * 32]);
  };

  f32x4 acc[4][4];
  f32x4 acc_e[4];
  const f32x4 z4 = {0.f, 0.f, 0.f, 0.f};
#pragma unroll
  for (int i = 0; i < 4; ++i) {
    acc_e[i] = z4;
#pragma unroll
    for (int j = 0; j < 4; ++j) acc[i][j] = z4;
  }

  // prologue: 3 tiles in flight
  stage(0); stage(1); stage(2);

#pragma unroll
  for (int t = 0; t < NT; ++t) {
    if (t + 3 < NT) stage(t + 3);
    if      (t < NT - 3) vmwait<12>();
    else if (t == NT - 3) vmwait<8>();
    else if (t == NT - 2) vmwait<4>();
    else                  vmwait<0>();
    __builtin_amdgcn_s_barrier();
    __builtin_amdgcn_sched_barrier(0);
    const int b = t & 3;
    bf16x8 af[4], bfv[4];
#pragma unroll
    for (int i = 0; i < 4; ++i) {
      const int row = wr0 + i * 16 + ln;
      af[i] = *(const bf16x8*)(&As[b][row * 32 + ((quad ^ (ln & 3)) << 3)]);
    }
#pragma unroll
    for (int j = 0; j < 4; ++j) {
      const int row = wc0 + j * 16 + ln;
      bfv[j] = *(const bf16x8*)(&Bs[b][row * 32 + ((quad ^ (ln & 3)) << 3)]);
    }
#pragma unroll
    for (int i = 0; i < 4; ++i)
#pragma unroll
      for (int j = 0; j < 4; ++j)
        acc[i][j] = __builtin_amdgcn_mfma_f32_16x16x32_bf16(af[i], bfv[j], acc[i][j], 0, 0, 0);
    if (do_e) {
      bf16x8 bfe = *(const bf16x8*)(&Be[ln * LDE + t * 32 + quad * 8]);
#pragma unroll
      for (int i = 0; i < 4; ++i)
        acc_e[i] = __builtin_amdgcn_mfma_f32_16x16x32_bf16(af[i], bfe, acc_e[i], 0, 0, 0);
    }
    __builtin_amdgcn_sched_barrier(0);
    __builtin_amdgcn_s_barrier();
  }
  __syncthreads();   // all waves done with LDS -> reuse As as epilogue scratch

  // ---- epilogue phase A: pack C tile into LDS; store es/ed direct from acc_e ----
  unsigned int* Cb = (unsigned int*)As;      // 128*36*4 = 18.4 KB
  const int cbase = (wc0 >> 2) + ln;
#pragma unroll
  for (int i = 0; i < 4; ++i) {
#pragma unroll
    for (int r = 0; r < 4; ++r) {
      int rowl = wr0 + i * 16 + quad * 4 + r;
      int p = __builtin_amdgcn_cvt_pk_fp8_f32(acc[i][0][r], acc[i][1][r], 0, false);
      p     = __builtin_amdgcn_cvt_pk_fp8_f32(acc[i][2][r], acc[i][3][r], p, true);
      Cb[rowl * 36 + cbase] = (unsigned int)p;
    }
  }
  if (do_e) {
#pragma unroll
    for (int i = 0; i < 4; ++i) {
#pragma unroll
      for (int r = 0; r < 4; ++r) {
        int row = bm + wr0 + i * 16 + quad * 4 + r;
        if (row < M && ln < 8) {
          float* dst = (ln < 4) ? es : ed;
          dst[(size_t)row * nh + (ln & 3)] = acc_e[i][r];
        }
      }
    }
  }
  __syncthreads();

  // ---- epilogue phase B: coalesced C store ----
  {
    const int rT = tid >> 1;          // 0..127
    const int hT = tid & 1;           // col-half 64*hT
    const unsigned int* cp = &Cb[rT * 36 + 16 * hT];
    uint4 d0 = *(const uint4*)(cp + 0);
    uint4 d1 = *(const uint4*)(cp + 4);
    uint4 d2 = *(const uint4*)(cp + 8);
    uint4 d3 = *(const uint4*)(cp + 12);
    int grow = bm + rT;
    if (grow < M) {
      unsigned char* gp = Cout + (size_t)grow * N + bn + 64 * hT;
      uint4 o;
      o.x = bsel(d0, 0); o.y = bsel(d1, 0); o.z = bsel(d2, 0); o.w = bsel(d3, 0);
      *(uint4*)(gp + 0) = o;
      o.x = bsel(d0, 1); o.y = bsel(d1, 1); o.z = bsel(d2, 1); o.w = bsel(d3, 1);
      *(uint4*)(gp + 16) = o;
      o.x = bsel(d0, 2); o.y = bsel(d1, 2); o.z = bsel(d2, 2); o.w = bsel(d3, 2);
      *(uint4*)(gp + 32) = o;
      o.x = bsel(d0, 3); o.y = bsel(d1, 3); o.z = bsel(d2, 3); o.w = bsel(d3, 3);
      *(uint4*)(gp + 48) = o;
    }
  }
}

// ---------------- skinny MFMA GEMM, N=64, split-K, fp32 partials ----------------
__global__ __launch_bounds__(256) void gemm_mfma_n64(
    const unsigned short* __restrict__ A, int lda,
    const unsigned short* __restrict__ BT, int ldb,
    float* __restrict__ Cp, int M, int kchunk)
{
  const int LDT = 72;
  __shared__ unsigned short As[128 * 72];
  __shared__ unsigned short Bs[64 * 72];
  const int tid  = threadIdx.x;
  const int wave = tid >> 6;
  const int lane = tid & 63;
  const int ln   = lane & 15;
  const int quad = lane >> 4;
  const int ks   = blockIdx.x;
  const int bm   = blockIdx.y * 128;
  const int k_beg = ks * kchunk;
  const int k_end = k_beg + kchunk;
  const int arow = tid >> 1;
  const int akb  = (tid & 1) * 32;
  const int brow = tid >> 2;
  const int bkb  = (tid & 3) * 16;

  f32x4 acc[2][4];
  const f32x4 z4 = {0.f, 0.f, 0.f, 0.f};
#pragma unroll
  for (int i = 0; i < 2; ++i)
#pragma unroll
    for (int j = 0; j < 4; ++j) acc[i][j] = z4;

  for (int k0 = k_beg; k0 < k_end; k0 += 64) {
    const unsigned short* ap = A + (size_t)(bm + arow) * lda + k0 + akb;
#pragma unroll
    for (int q = 0; q < 4; ++q)
      *(bf16x8*)(&As[arow * LDT + akb + q * 8]) = *(const bf16x8*)(ap + q * 8);
    const unsigned short* bp = BT + (size_t)brow * ldb + k0 + bkb;
#pragma unroll
    for (int q = 0; q < 2; ++q)
      *(bf16x8*)(&Bs[brow * LDT + bkb + q * 8]) = *(const bf16x8*)(bp + q * 8);
    __syncthreads();
#pragma unroll
    for (int kk = 0; kk < 2; ++kk) {
      bf16x8 af[2], bfv[4];
#pragma unroll
      for (int i = 0; i < 2; ++i)
        af[i] = *(const bf16x8*)(&As[(wave * 32 + i * 16 + ln) * LDT + kk * 32 + quad * 8]);
#pragma unroll
      for (int j = 0; j < 4; ++j)
        bfv[j] = *(const bf16x8*)(&Bs[(j * 16 + ln) * LDT + kk * 32 + quad * 8]);
#pragma unroll
      for (int i = 0; i < 2; ++i)
#pragma unroll
        for (int j = 0; j < 4; ++j)
          acc[i][j] = __builtin_amdgcn_mfma_f32_16x16x32_bf16(af[i], bfv[j], acc[i][j], 0, 0, 0);
    }
    __syncthreads();
  }
#pragma unroll
  for (int i = 0; i < 2; ++i)
#pragma unroll
    for (int r = 0; r < 4; ++r) {
      int row = bm + wave * 32 + i * 16 + quad * 4 + r;
#pragma unroll
      for (int j = 0; j < 4; ++j)
        Cp[((size_t)ks * M + row) * 64 + j * 16 + ln] = acc[i][j][r];
    }
}

// ---------------- fp partial reduce + bias -> bf16 into z cols [512,576) ----------------
__global__ void fp_finish(const float* __restrict__ Cp, int ksplit, int M,
                          const float* __restrict__ bfp,
                          unsigned short* __restrict__ zb)
{
  const int g = blockIdx.x;
  const int j = threadIdx.x;
  float s = bfp[j];
  for (int ks = 0; ks < ksplit; ++ks) s += Cp[((size_t)ks * M + g) * 64 + j];
  zb[(size_t)g * 576 + 512 + j] = f2b_rne(s);
}

// ---------------- mlp partial reduce + bias + relu + fc2 dot -> out ----------------
__global__ void mlp_finish(const float* __restrict__ Cp, int ksplit, int M,
                           const float* __restrict__ bfc1,
                           const float* __restrict__ Wfc2, const float* __restrict__ bfc2,
                           float* __restrict__ out)
{
  const int g = blockIdx.x;
  const int j = threadIdx.x;
  float s = bfc1[j];
  for (int ks = 0; ks < ksplit; ++ks) s += Cp[((size_t)ks * M + g) * 64 + j];
  s = s > 0.f ? s : 0.f;
  float term = s * Wfc2[j];
  for (int off = 32; off; off >>= 1) term += __shfl_down(term, off, 64);
  if (j == 0) out[g] = term + bfc2[0];
}

// ---------------- fused count: edge degrees + graph counts ----------------
__global__ void count_all(const int* __restrict__ ei, int E, int* __restrict__ deg,
                          const int* __restrict__ batch, int NN, int* __restrict__ gcnt,
                          int BE)
{
  int b = blockIdx.x;
  int t = threadIdx.x;
  if (b < BE) {
    int e = b * 256 + t;
    if (e < E) atomicAdd(&deg[ei[E + e]], 1);
  } else {
    int i = (b - BE) * 256 + t;
    if (i < NN) atomicAdd(&gcnt[batch[i]], 1);
  }
}

__global__ void fill_csr(const int* __restrict__ ei, int E, int* __restrict__ cursor,
                         const int* __restrict__ rowptr, int* __restrict__ csr_src)
{
  int e = blockIdx.x * 256 + threadIdx.x;
  if (e < E) {
    int d = ei[E + e];
    int pos = atomicAdd(&cursor[d], 1);
    csr_src[rowptr[d] + pos] = ei[e];
  }
}

// ---------------- fused 3-phase exclusive scans ----------------
__device__ void scan_p1_body(const int* __restrict__ vals, int n, int* __restrict__ bsum,
                             int bb)
{
  __shared__ int red[256];
  int base = bb * 1024;
  int t = threadIdx.x;
  int s = 0;
#pragma unroll
  for (int i = 0; i < 4; ++i) {
    int idx = base + i * 256 + t;
    if (idx < n) s += vals[idx];
  }
  red[t] = s;
  __syncthreads();
  for (int off = 128; off; off >>= 1) {
    if (t < off) red[t] += red[t + off];
    __syncthreads();
  }
  if (t == 0) bsum[bb] = red[0];
}

__global__ void scan2_p1(const int* __restrict__ vA, int nA, int* __restrict__ bsA, int nbA,
                         const int* __restrict__ vB, int nB, int* __restrict__ bsB)
{
  int b = blockIdx.x;
  if (b < nbA) scan_p1_body(vA, nA, bsA, b);
  else         scan_p1_body(vB, nB, bsB, b - nbA);
}

__device__ void scan_p2_body(const int* __restrict__ bsum, int* __restrict__ bpre,
                             int nb, int* __restrict__ rowptr, int n)
{
  __shared__ int tmp[128];
  int t = threadIdx.x;
  int v = (t < nb) ? bsum[t] : 0;
  tmp[t] = v;
  __syncthreads();
  for (int off = 1; off < 128; off <<= 1) {
    int add = (t >= off) ? tmp[t - off] : 0;
    __syncthreads();
    tmp[t] += add;
    __syncthreads();
  }
  if (t < nb) bpre[t] = tmp[t] - v;
  if (t == 127) rowptr[n] = tmp[127];
}

__global__ void scan2_p2(const int* __restrict__ bsA, int* __restrict__ bpA, int nbA,
                         int* __restrict__ rpA, int nA,
                         const int* __restrict__ bsB, int* __restrict__ bpB, int nbB,
                         int* __restrict__ rpB, int nB)
{
  if (blockIdx.x == 0) scan_p2_body(bsA, bpA, nbA, rpA, nA);
  else                 scan_p2_body(bsB, bpB, nbB, rpB, nB);
}

__device__ void scan_p3_body(const int* __restrict__ vals, const int* __restrict__ bpre,
                             int n, int* __restrict__ rowptr, int bb)
{
  __shared__ int tmp[256];
  int t = threadIdx.x;
  int base = bb * 1024 + t * 4;
  int v[4]; int s = 0;
#pragma unroll
  for (int i = 0; i < 4; ++i) {
    int idx = base + i;
    v[i] = (idx < n) ? vals[idx] : 0;
    s += v[i];
  }
  tmp[t] = s;
  __syncthreads();
  for (int off = 1; off < 256; off <<= 1) {
    int add = (t >= off) ? tmp[t - off] : 0;
    __syncthreads();
    tmp[t] += add;
    __syncthreads();
  }
  int run = bpre[bb] + tmp[t] - s;
#pragma unroll
  for (int i = 0; i < 4; ++i) {
    int idx = base + i;
    if (idx < n) rowptr[idx] = run;
    run += v[i];
  }
}

__global__ void scan2_p3(const int* __restrict__ vA, const int* __restrict__ bpA, int nA,
                         int* __restrict__ rpA, int nbA,
                         const int* __restrict__ vB, const int* __restrict__ bpB, int nB,
                         int* __restrict__ rpB)
{
  int b = blockIdx.x;
  if (b < nbA) scan_p3_body(vA, bpA, nA, rpA, b);
  else         scan_p3_body(vB, bpB, nB, rpB, b - nbA);
}

// ---------------- attention weights, one pass: unnormalized w + dinv ----------------
__global__ void alpha_kernel(const float* __restrict__ es, const float* __restrict__ ed,
                             const int* __restrict__ rowptr, const int* __restrict__ csr_src,
                             float* __restrict__ w_csr, float* __restrict__ wself,
                             float* __restrict__ dinv, int N, int nh)
{
  int idx = blockIdx.x * 256 + threadIdx.x;
  if (idx >= N * nh) return;
  const int dst = idx / nh;
  const int h = idx - dst * nh;
  const float edh = ed[(size_t)dst * nh + h];
  const int beg = rowptr[dst], end = rowptr[dst + 1];
  float sum = 0.f;
  for (int e = beg; e < end; ++e) {
    int s = csr_src[e];
    float l = es[(size_t)s * nh + h] + edh;
    l = l >= 0.f ? l : NEG_SLOPE * l;
    float w = expf(l);
    w_csr[(size_t)e * nh + h] = w;
    sum += w;
  }
  float ls = es[(size_t)dst * nh + h] + edh;
  ls = ls >= 0.f ? ls : NEG_SLOPE * ls;
  float wsl = expf(ls);
  sum += wsl;
  wself[(size_t)dst * nh + h] = wsl;
  dinv[(size_t)dst * nh + h] = 1.0f / sum;
}

// ---------------- conv1 aggregate: ONE WAVE PER DST (wave-uniform edge loop),
// 4 ch/lane (64 lanes x 4 = 256), fp8 gather 4-deep MLP + dinv + bias + ELU -> bf16 ----
__global__ __launch_bounds__(256) void aggregate_b(
    const unsigned char* __restrict__ h,
    const float* __restrict__ w_csr, const float* __restrict__ wself,
    const float* __restrict__ dinv,
    const int* __restrict__ rowptr, const int* __restrict__ csr_src,
    const float* __restrict__ bias, unsigned short* __restrict__ out,
    int N, int nh, int C)
{
  const int HC = nh * C;                 // 256
  const int wave = threadIdx.x >> 6;     // 0..3
  const int lane = threadIdx.x & 63;
  const int dst = blockIdx.x * 4 + wave;
  if (dst >= N) return;
  const int ch = lane << 2;              // 4 channels per lane
  const int head = ch / C;               // lane/16 for C=64
  const int beg = rowptr[dst], end = rowptr[dst + 1];
  f32x2 acc2[2];
  acc2[0][0] = 0.f; acc2[0][1] = 0.f; acc2[1][0] = 0.f; acc2[1][1] = 0.f;
  int e = beg;
  for (; e + 3 < end; e += 4) {
    int s0 = csr_src[e], s1 = csr_src[e + 1], s2 = csr_src[e + 2], s3 = csr_src[e + 3];
    float a0 = w_csr[(size_t)e * nh + head];
    float a1 = w_csr[(size_t)(e + 1) * nh + head];
    float a2 = w_csr[(size_t)(e + 2) * nh + head];
    float a3 = w_csr[(size_t)(e + 3) * nh + head];
    unsigned int r0 = *(const unsigned int*)(h + (size_t)s0 * HC + ch);
    unsigned int r1 = *(const unsigned int*)(h + (size_t)s1 * HC + ch);
    unsigned int r2 = *(const unsigned int*)(h + (size_t)s2 * HC + ch);
    unsigned int r3 = *(const unsigned int*)(h + (size_t)s3 * HC + ch);
    acc4_fp8(r0, a0, acc2); acc4_fp8(r1, a1, acc2);
    acc4_fp8(r2, a2, acc2); acc4_fp8(r3, a3, acc2);
  }
  for (; e < end; ++e) {
    int s0 = csr_src[e];
    float a0 = w_csr[(size_t)e * nh + head];
    unsigned int r0 = *(const unsigned int*)(h + (size_t)s0 * HC + ch);
    acc4_fp8(r0, a0, acc2);
  }
  {
    float a = wself[(size_t)dst * nh + head];
    unsigned int r0 = *(const unsigned int*)(h + (size_t)dst * HC + ch);
    acc4_fp8(r0, a, acc2);
  }
  const float di = dinv[(size_t)dst * nh + head];
  bf16x4 o;
#pragma unroll
  for (int q = 0; q < 2; ++q) {
#pragma unroll
    for (int u = 0; u < 2; ++u) {
      float v = acc2[q][u] * di + bias[ch + q * 2 + u];
      v = v > 0.f ? v : (expf(v) - 1.0f);
      o[q * 2 + u] = (short)f2b_rne(v);
    }
  }
  *(bf16x4*)(out + (size_t)dst * HC + ch) = o;
}

// ---------------- conv2 aggregate + ELU + mean-pool: 4 blocks/graph, unroll-4,
// LDS reduce, ONE atomicAdd per channel per block-part ----------------
__global__ __launch_bounds__(256) void agg_pool_split(
    const unsigned char* __restrict__ h,
    const float* __restrict__ w_csr, const float* __restrict__ wself,
    const float* __restrict__ dinv,
    const int* __restrict__ rowptr, const int* __restrict__ csr_src,
    const float* __restrict__ bias, const int* __restrict__ grp,
    float* __restrict__ pool)
{
  const int g = blockIdx.x >> 2;
  const int part = blockIdx.x & 3;
  const int wave = threadIdx.x >> 6;   // 0..3
  const int lane = threadIdx.x & 63;
  const int ch = lane << 3;
  const int head = lane >> 4;          // ch/128
  const int gbeg = grp[g], gend = grp[g + 1];
  float bch[8];
#pragma unroll
  for (int r = 0; r < 8; ++r) bch[r] = bias[ch + r];
  f32x2 pool2[4];
#pragma unroll
  for (int q = 0; q < 4; ++q) { pool2[q][0] = 0.f; pool2[q][1] = 0.f; }

  for (int node = gbeg + part * 4 + wave; node < gend; node += 16) {
    const int beg = rowptr[node], end = rowptr[node + 1];
    f32x2 acc2[4];
#pragma unroll
    for (int q = 0; q < 4; ++q) { acc2[q][0] = 0.f; acc2[q][1] = 0.f; }
    int e = beg;
    for (; e + 3 < end; e += 4) {
      int s0 = csr_src[e], s1 = csr_src[e + 1], s2 = csr_src[e + 2], s3 = csr_src[e + 3];
      float a0 = w_csr[(size_t)e * 4 + head];
      float a1 = w_csr[(size_t)(e + 1) * 4 + head];
      float a2 = w_csr[(size_t)(e + 2) * 4 + head];
      float a3 = w_csr[(size_t)(e + 3) * 4 + head];
      uint2 r0 = *(const uint2*)(h + (size_t)s0 * 512 + ch);
      uint2 r1 = *(const uint2*)(h + (size_t)s1 * 512 + ch);
      uint2 r2 = *(const uint2*)(h + (size_t)s2 * 512 + ch);
      uint2 r3 = *(const uint2*)(h + (size_t)s3 * 512 + ch);
      acc8_fp8(r0, a0, acc2); acc8_fp8(r1, a1, acc2);
      acc8_fp8(r2, a2, acc2); acc8_fp8(r3, a3, acc2);
    }
    for (; e < end; ++e) {
      int s0 = csr_src[e];
      float a0 = w_csr[(size_t)e * 4 + head];
      uint2 r0 = *(const uint2*)(h + (size_t)s0 * 512 + ch);
      acc8_fp8(r0, a0, acc2);
    }
    {
      float a = wself[(size_t)node * 4 + head];
      uint2 r0 = *(const uint2*)(h + (size_t)node * 512 + ch);
      acc8_fp8(r0, a, acc2);
    }
    const float di = dinv[(size_t)node * 4 + head];
#pragma unroll
    for (int q = 0; q < 4; ++q) {
#pragma unroll
      for (int u = 0; u < 2; ++u) {
        float v = acc2[q][u] * di + bch[q * 2 + u];
        v = v > 0.f ? v : (expf(v) - 1.0f);   // ELU
        pool2[q][u] += v;
      }
    }
  }

  __shared__ float red[4][512];   // 8 KB
#pragma unroll
  for (int q = 0; q < 4; ++q) {
    red[wave][ch + 2 * q]     = pool2[q][0];
    red[wave][ch + 2 * q + 1] = pool2[q][1];
  }
  __syncthreads();
#pragma unroll
  for (int k = 0; k < 2; ++k) {
    int c = threadIdx.x + k * 256;
    float s = (red[0][c] + red[1][c]) + (red[2][c] + red[3][c]);
    atomicAdd(&pool[(size_t)g * 512 + c], s);
  }
}

// ---------------- pool scale + bf16 pack into zb cols [0,512) ----------------
__global__ void pool_finish(const float* __restrict__ pool, const int* __restrict__ rpg,
                            unsigned short* __restrict__ zb)
{
  const int g = blockIdx.x;
  const int c = threadIdx.x;   // 0..511
  const int cnt = rpg[g + 1] - rpg[g];
  const float inv = 1.0f / (float)(cnt > 1 ? cnt : 1);
  zb[(size_t)g * 576 + c] = f2b_rne(pool[(size_t)g * 512 + c] * inv);
}

// ---------------- launcher ----------------
extern "C" void kernel_launch(void* const* d_in, const int* in_sizes, int n_in,
                              void* d_out, int out_size, void* d_ws, size_t ws_size,
                              hipStream_t stream)
{
  const float* x      = (const float*)d_in[0];
  const int*   ei     = (const int*)d_in[1];
  const int*   batch  = (const int*)d_in[2];
  const float* fp     = (const float*)d_in[3];
  const float* W1     = (const float*)d_in[4];
  const float* a_src1 = (const float*)d_in[5];
  const float* a_dst1 = (const float*)d_in[6];
  const float* b1     = (const float*)d_in[7];
  const float* W2     = (const float*)d_in[8];
  const float* a_src2 = (const float*)d_in[9];
  const float* a_dst2 = (const float*)d_in[10];
  const float* b2     = (const float*)d_in[11];
  const float* Wfp    = (const float*)d_in[12];
  const float* bfp    = (const float*)d_in[13];
  const float* Wfc1   = (const float*)d_in[14];
  const float* bfc1   = (const float*)d_in[15];
  const float* Wfc2   = (const float*)d_in[16];
  const float* bfc2   = (const float*)d_in[17];
  float* out = (float*)d_out;

  const int NN = in_sizes[0] / 128;
  const int E  = in_sizes[1] / 2;
  const int G  = in_sizes[3] / 2048;
  const int FIN = 128, H = 4, C1 = 64, C2 = 128;
  const int HC1 = H * C1;   // 256
  const int HC2 = H * C2;   // 512
  const int KFP = in_sizes[3] / G;   // 2048
  const int KZ  = HC2 + 64;          // 576
  const int KS_FP = 16;
  const int KS_Z  = 9;

  // ---- workspace: liverange-overlaid regions ----
  char* base = (char*)d_ws;
  size_t off = 0;
  auto alloc = [&](size_t bytes) {
    char* p = base + off; off += (bytes + 255) & ~(size_t)255; return p;
  };
  // Region A: early xb(bf16)+h1b(fp8); late h2b(fp8)
  size_t xb_sz  = ((size_t)NN * FIN * 2 + 255) & ~(size_t)255;
  size_t h1b_sz = (size_t)NN * HC1;        // fp8: 1 B/elem
  size_t h2b_sz = (size_t)NN * HC2;        // fp8
  size_t rA = xb_sz + h1b_sz; if (h2b_sz > rA) rA = h2b_sz;
  char* RA = alloc(rA);
  unsigned short* xb  = (unsigned short*)RA;
  unsigned char*  h1b = (unsigned char*)(RA + xb_sz);
  unsigned char*  h2b = (unsigned char*)RA;
  // Region B: early fpb+Cp_fp; late agg1b (bf16 — GEMM input)
  size_t fpb_sz  = ((size_t)G * KFP * 2 + 255) & ~(size_t)255;
  size_t cpfp_sz = (size_t)KS_FP * G * 64 * 4;
  size_t agg1_sz = (size_t)NN * HC1 * 2;
  size_t rB = fpb_sz + cpfp_sz; if (agg1_sz > rB) rB = agg1_sz;
  char* RB = alloc(rB);
  unsigned short* fpb   = (unsigned short*)RB;
  float*          Cp_fp = (float*)(RB + fpb_sz);
  unsigned short* agg1b = (unsigned short*)RB;
  // Region C: attn buffers (conv1 then conv2 sequentially)
  float* w1     = (float*)alloc((size_t)E * H * 4);
  float* wself1 = (float*)alloc((size_t)NN * H * 4);
  float* es1    = (float*)alloc((size_t)NN * H * 4);
  float* ed1    = (float*)alloc((size_t)NN * H * 4);
  float* dinv1  = (float*)alloc((size_t)NN * H * 4);
  float* w2 = w1, *wself2 = wself1, *es2 = es1, *ed2 = ed1, *dinv2 = dinv1;
  // Persistent small buffers
  unsigned short* zb    = (unsigned short*)alloc((size_t)G * KZ * 2);
  float*          Cp_z  = (float*)alloc((size_t)KS_Z * G * 64 * 4);
  float*          pool  = (float*)alloc((size_t)G * HC2 * 4);   // 4 MB
  unsigned short* W1T   = (unsigned short*)alloc((size_t)HC1 * FIN * 2);
  unsigned short* W2T   = (unsigned short*)alloc((size_t)HC2 * HC1 * 2);
  unsigned short* WfpT  = (unsigned short*)alloc((size_t)64 * KFP * 2);
  unsigned short* Wfc1T = (unsigned short*)alloc((size_t)64 * KZ * 2);
  unsigned short* BeT1  = (unsigned short*)alloc((size_t)8 * 128 * 2);
  unsigned short* BeT2  = (unsigned short*)alloc((size_t)8 * 256 * 2);
  // int arena: deg/cursor/gcnt contiguous (single memset covers exactly this span)
  int* iarena   = (int*)alloc(((size_t)2 * NN + G) * 4);
  int* deg      = iarena;
  int* cursor   = iarena + NN;
  int* gcnt     = iarena + 2 * NN;
  int* rowptr_n = (int*)alloc(((size_t)NN + 1) * 4);
  int* rowptr_g = (int*)alloc(((size_t)G + 1) * 4);
  int* csr_src  = (int*)alloc((size_t)E * 4);
  int* bsumA    = (int*)alloc(128 * 4);
  int* bpreA    = (int*)alloc(128 * 4);
  int* bsumB    = (int*)alloc(128 * 4);
  int* bpreB    = (int*)alloc(128 * 4);

  // zero the atomic pool early (overlaps with prep work)
  hipMemsetAsync(pool, 0, (size_t)G * HC2 * 4, stream);

  // ---- fused prep ----
  const size_t nx = (size_t)NN * FIN;
  const size_t nf = (size_t)G * KFP;
  const int B0 = (int)((nx + 255) / 256);
  const int B1 = (int)((nf + 255) / 256);
  {
    int nb = B0 + B1 + 128 + 512 + 512 + 144;
    prep_all<<<nb, 256, 0, stream>>>(x, xb, nx, B0, fp, fpb, nf, B1,
                                     W1, W1T, W2, W2T, Wfp, WfpT, Wfc1, Wfc1T);
  }
  prep_e<<<8, 256, 0, stream>>>(W1, a_src1, a_dst1, W2, a_src2, a_dst2, BeT1, BeT2);

  // ---- fingerprint branch ----
  {
    dim3 gg(KS_FP, G / 128);
    gemm_mfma_n64<<<gg, 256, 0, stream>>>(fpb, KFP, WfpT, KFP, Cp_fp, G, KFP / KS_FP);
    fp_finish<<<G, 64, 0, stream>>>(Cp_fp, KS_FP, G, bfp, zb);
  }

  // ---- CSR by dst + graph segment ptrs ----
  hipMemsetAsync(iarena, 0, sizeof(int) * ((size_t)2 * NN + G), stream);
  {
    int BE = (E + 255) / 256;
    int BN = (NN + 255) / 256;
    count_all<<<BE + BN, 256, 0, stream>>>(ei, E, deg, batch, NN, gcnt, BE);
  }
  {
    int nbA = (NN + 1023) / 1024;
    int nbB = (G + 1023) / 1024;
    scan2_p1<<<nbA + nbB, 256, 0, stream>>>(deg, NN, bsumA, nbA, gcnt, G, bsumB);
    scan2_p2<<<2, 128, 0, stream>>>(bsumA, bpreA, nbA, rowptr_n, NN,
                                    bsumB, bpreB, nbB, rowptr_g, G);
    scan2_p3<<<nbA + nbB, 256, 0, stream>>>(deg, bpreA, NN, rowptr_n, nbA,
                                            gcnt, bpreB, G, rowptr_g);
  }
  fill_csr<<<(E + 255) / 256, 256, 0, stream>>>(ei, E, cursor, rowptr_n, csr_src);

  // ---- conv1: GEMM (fp8 h1 + fused e-cols) -> alpha -> aggregate ----
  {
    const int nrow = (NN + 127) / 128;
    gemm_mfma<128><<<nrow * (HC1 / 128), 256, 0, stream>>>(
        xb, W1T, h1b, NN, HC1, BeT1, es1, ed1, H);
  }
  alpha_kernel<<<(NN * H + 255) / 256, 256, 0, stream>>>(es1, ed1, rowptr_n, csr_src,
                                                         w1, wself1, dinv1, NN, H);
  aggregate_b<<<(NN + 3) / 4, 256, 0, stream>>>(h1b, w1, wself1, dinv1, rowptr_n, csr_src,
                                                b1, agg1b, NN, H, C1);

  // ---- conv2: GEMM (fp8 h2 + fused e-cols) -> alpha -> split pool ----
  {
    const int nrow = (NN + 127) / 128;
    gemm_mfma<256><<<nrow * (HC2 / 128), 256, 0, stream>>>(
        agg1b, W2T, h2b, NN, HC2, BeT2, es2, ed2, H);
  }
  alpha_kernel<<<(NN * H + 255) / 256, 256, 0, stream>>>(es2, ed2, rowptr_n, csr_src,
                                                         w2, wself2, dinv2, NN, H);
  agg_pool_split<<<G * 4, 256, 0, stream>>>(h2b, w2, wself2, dinv2, rowptr_n, csr_src,
                                            b2, rowptr_g, pool);
  pool_finish<<<G, 512, 0, stream>>>(pool, rowptr_g, zb);

  // ---- head ----
  {
    dim3 gg(KS_Z, G / 128);
    gemm_mfma_n64<<<gg, 256, 0, stream>>>(zb, KZ, Wfc1T, KZ, Cp_z, G, KZ / KS_Z);
    mlp_finish<<<G, 64, 0, stream>>>(Cp_z, KS_Z, G, bfc1, Wfc2, bfc2, out);
  }
}

// Round 9
// 447.309 us; speedup vs baseline: 1.0652x; 1.0652x over previous
//
#include <hip/hip_runtime.h>
#include <math.h>

#define NEG_SLOPE 0.2f

typedef __attribute__((ext_vector_type(8))) short bf16x8;   // 8 bf16 (4 VGPRs)
typedef __attribute__((ext_vector_type(4))) float f32x4;    // MFMA acc
typedef __attribute__((ext_vector_type(2))) float f32x2;

__device__ __forceinline__ float b2f(short s) {
  return __uint_as_float(((unsigned int)(unsigned short)s) << 16);
}
__device__ __forceinline__ unsigned short f2b_rne(float f) {
  unsigned int u = __float_as_uint(f);
  u = (u + 0x7FFF + ((u >> 16) & 1)) >> 16;
  return (unsigned short)u;
}

// 8 fp8(e4m3) bytes -> 8 floats (HW cvt)
__device__ __forceinline__ void fp8x8_to_f32(uint2 raw, float* f) {
  f32x2 a = __builtin_amdgcn_cvt_pk_f32_fp8((int)raw.x, false);
  f32x2 b = __builtin_amdgcn_cvt_pk_f32_fp8((int)raw.x, true);
  f32x2 c = __builtin_amdgcn_cvt_pk_f32_fp8((int)raw.y, false);
  f32x2 d = __builtin_amdgcn_cvt_pk_f32_fp8((int)raw.y, true);
  f[0] = a[0]; f[1] = a[1]; f[2] = b[0]; f[3] = b[1];
  f[4] = c[0]; f[5] = c[1]; f[6] = d[0]; f[7] = d[1];
}

// async global->LDS, 16B per lane; LDS dest is wave-uniform base + lane*16
__device__ __forceinline__ void gload16(const unsigned short* g, unsigned short* l) {
  __builtin_amdgcn_global_load_lds(
      (const __attribute__((address_space(1))) unsigned int*)g,
      (__attribute__((address_space(3))) unsigned int*)l, 16, 0, 0);
}

template<int N> __device__ __forceinline__ void vmwait() {
  asm volatile("s_waitcnt vmcnt(%0)" :: "n"(N) : "memory");
}

// byte s of each of 4 dwords -> packed dword
__device__ __forceinline__ unsigned int bsel(uint4 d, int s) {
  return ((d.x >> (8 * s)) & 0xffu) | (((d.y >> (8 * s)) & 0xffu) << 8)
       | (((d.z >> (8 * s)) & 0xffu) << 16) | (((d.w >> (8 * s)) & 0xffu) << 24);
}

// ---------------- fused prep: cvt x, cvt fp, 4 weight transposes ----------------
__device__ __forceinline__ void tr_one(const float* __restrict__ W,
                                       unsigned short* __restrict__ WT,
                                       int K, int N, int idx)
{
  if (idx < K * N) {
    int k = idx / N, n = idx - k * N;
    WT[(size_t)n * K + k] = f2b_rne(W[idx]);
  }
}

__global__ __launch_bounds__(256) void prep_all(
    const float* __restrict__ x, unsigned short* __restrict__ xb, size_t nx, int B0,
    const float* __restrict__ fp, unsigned short* __restrict__ fpb, size_t nf, int B1,
    const float* __restrict__ W1, unsigned short* __restrict__ W1T,
    const float* __restrict__ W2, unsigned short* __restrict__ W2T,
    const float* __restrict__ Wfp, unsigned short* __restrict__ WfpT,
    const float* __restrict__ Wfc1, unsigned short* __restrict__ Wfc1T)
{
  int b = blockIdx.x;
  const int t = threadIdx.x;
  if (b < B0) {
    size_t i = (size_t)b * 256 + t;
    if (i < nx) xb[i] = f2b_rne(x[i]);
    return;
  }
  b -= B0;
  if (b < B1) {
    size_t i = (size_t)b * 256 + t;
    if (i < nf) fpb[i] = f2b_rne(fp[i]);
    return;
  }
  b -= B1;
  if (b < 128) { tr_one(W1, W1T, 128, 256, b * 256 + t); return; }
  b -= 128;
  if (b < 512) { tr_one(W2, W2T, 256, 512, b * 256 + t); return; }
  b -= 512;
  if (b < 512) { tr_one(Wfp, WfpT, 2048, 64, b * 256 + t); return; }
  b -= 512;
  tr_one(Wfc1, Wfc1T, 576, 64, b * 256 + t);
}

// ---------------- e-projection prep: BeT[ecol][k] = bf16( sum_c W[k][h*C+c]*a[h][c] ) ----
__global__ __launch_bounds__(256) void prep_e(
    const float* __restrict__ W1, const float* __restrict__ as1, const float* __restrict__ ad1,
    const float* __restrict__ W2, const float* __restrict__ as2, const float* __restrict__ ad2,
    unsigned short* __restrict__ BeT1, unsigned short* __restrict__ BeT2)
{
  const int b = blockIdx.x;
  const int k = threadIdx.x;
  if (b < 4) {                       // conv1: K=128, C=64, N=256
    if (k < 128) {
      float ss = 0.f, sd = 0.f;
      for (int c = 0; c < 64; ++c) {
        float w = W1[k * 256 + b * 64 + c];
        ss += w * as1[b * 64 + c];
        sd += w * ad1[b * 64 + c];
      }
      BeT1[b * 128 + k] = f2b_rne(ss);
      BeT1[(4 + b) * 128 + k] = f2b_rne(sd);
    }
  } else {                           // conv2: K=256, C=128, N=512
    const int h = b - 4;
    float ss = 0.f, sd = 0.f;
    for (int c = 0; c < 128; ++c) {
      float w = W2[k * 512 + h * 128 + c];
      ss += w * as2[h * 128 + c];
      sd += w * ad2[h * 128 + c];
    }
    BeT2[h * 256 + k] = f2b_rne(ss);
    BeT2[(4 + h) * 256 + k] = f2b_rne(sd);
  }
}

// ---------------- MFMA GEMM; C in fp8(e4m3); es/ed as extra MFMA columns ----------------
template<int KK>
__global__ __launch_bounds__(256) void gemm_mfma(
    const unsigned short* __restrict__ A, const unsigned short* __restrict__ BT,
    unsigned char* __restrict__ Cout, int M, int N,
    const unsigned short* __restrict__ BeT,
    float* __restrict__ es, float* __restrict__ ed, int nh)
{
  constexpr int NT = KK / 32;          // 4 (conv1) or 8 (conv2)
  constexpr int LDE = KK + 8;          // Be stride (2-way-free banking)
  __shared__ unsigned short As[4][128 * 32];   // 32 KB
  __shared__ unsigned short Bs[4][128 * 32];   // 32 KB
  __shared__ unsigned short Be[16 * LDE];      // ~8 KB
  const int tid  = threadIdx.x;
  const int wave = tid >> 6;
  const int lane = tid & 63;
  const int ln   = lane & 15;
  const int quad = lane >> 4;
  const int wr0  = (wave >> 1) * 64;
  const int wc0  = (wave & 1) * 64;

  // XCD-bijective chunked swizzle (m204), col-fastest within an XCD chunk.
  const int nwg = gridDim.x;
  const int ncol = N >> 7;
  const int bid = blockIdx.x;
  const int qq = nwg >> 3, rr = nwg & 7;
  const int xc = bid & 7, io = bid >> 3;
  const int swz = (xc < rr ? xc * (qq + 1) : rr * (qq + 1) + (xc - rr) * qq) + io;
  const int bn = (swz % ncol) * 128;
  const int bm = (swz / ncol) * 128;
  const bool do_e = (bn == 0) && (wc0 == 0);

  // stage Be once (bn==0 blocks only): 8 rows x KK elems
  if (bn == 0 && tid < KK) {
    const int rrw = tid / (KK / 8);
    const int ccl = (tid % (KK / 8)) * 8;
    bf16x8 v = *(const bf16x8*)(BeT + rrw * KK + ccl);
    *(bf16x8*)(&Be[rrw * LDE + ccl]) = v;
  }
  __syncthreads();

  // staging: wave w owns tile rows [32w,32w+32) as two 16-row segments.
  const int srow = lane >> 2;
  const int cch  = lane & 3;
  const int rt0  = wave * 32 + srow;
  const int ksw  = ((cch ^ (srow & 3)) << 3);
  int ar0 = bm + rt0;      if (ar0 >= M) ar0 = M - 1;   // clamp tail rows
  int ar1 = bm + rt0 + 16; if (ar1 >= M) ar1 = M - 1;
  const unsigned short* gA0 = A + (size_t)ar0 * KK + ksw;
  const unsigned short* gA1 = A + (size_t)ar1 * KK + ksw;
  const unsigned short* gB0 = BT + (size_t)(bn + rt0) * KK + ksw;
  const unsigned short* gB1 = BT + (size_t)(bn + rt0 + 16) * KK + ksw;

  auto stage = [&](int T) {
    const int b = T & 3;
    const int kk = T * 32;
    gload16(gA0 + kk, &As[b][(wave * 32) * 32]);
    gload16(gA1 + kk, &As[b][(wave * 32 + 16) * 32]);
    gload16(gB0 + kk, &Bs[b][(wave * 32) * 32]);
    gload16(gB1 + kk, &Bs[b][(wave * 32 + 16) * 32]);
  };

  f32x4 acc[4][4];
  f32x4 acc_e[4];
  const f32x4 z4 = {0.f, 0.f, 0.f, 0.f};
#pragma unroll
  for (int i = 0; i < 4; ++i) {
    acc_e[i] = z4;
#pragma unroll
    for (int j = 0; j < 4; ++j) acc[i][j] = z4;
  }

  // prologue: 3 tiles in flight
  stage(0); stage(1); stage(2);

#pragma unroll
  for (int t = 0; t < NT; ++t) {
    if (t + 3 < NT) stage(t + 3);
    if      (t < NT - 3) vmwait<12>();
    else if (t == NT - 3) vmwait<8>();
    else if (t == NT - 2) vmwait<4>();
    else                  vmwait<0>();
    __builtin_amdgcn_s_barrier();
    __builtin_amdgcn_sched_barrier(0);
    const int b = t & 3;
    bf16x8 af[4], bfv[4];
#pragma unroll
    for (int i = 0; i < 4; ++i) {
      const int row = wr0 + i * 16 + ln;
      af[i] = *(const bf16x8*)(&As[b][row * 32 + ((quad ^ (ln & 3)) << 3)]);
    }
#pragma unroll
    for (int j = 0; j < 4; ++j) {
      const int row = wc0 + j * 16 + ln;
      bfv[j] = *(const bf16x8*)(&Bs[b][row * 32 + ((quad ^ (ln & 3)) << 3)]);
    }
#pragma unroll
    for (int i = 0; i < 4; ++i)
#pragma unroll
      for (int j = 0; j < 4; ++j)
        acc[i][j] = __builtin_amdgcn_mfma_f32_16x16x32_bf16(af[i], bfv[j], acc[i][j], 0, 0, 0);
    if (do_e) {
      bf16x8 bfe = *(const bf16x8*)(&Be[ln * LDE + t * 32 + quad * 8]);
#pragma unroll
      for (int i = 0; i < 4; ++i)
        acc_e[i] = __builtin_amdgcn_mfma_f32_16x16x32_bf16(af[i], bfe, acc_e[i], 0, 0, 0);
    }
    __builtin_amdgcn_sched_barrier(0);
    __builtin_amdgcn_s_barrier();
  }
  __syncthreads();   // all waves done with LDS -> reuse As as epilogue scratch

  // ---- epilogue phase A: pack C tile into LDS; store es/ed direct from acc_e ----
  unsigned int* Cb = (unsigned int*)As;      // 128*36*4 = 18.4 KB
  const int cbase = (wc0 >> 2) + ln;
#pragma unroll
  for (int i = 0; i < 4; ++i) {
#pragma unroll
    for (int r = 0; r < 4; ++r) {
      int rowl = wr0 + i * 16 + quad * 4 + r;
      int p = __builtin_amdgcn_cvt_pk_fp8_f32(acc[i][0][r], acc[i][1][r], 0, false);
      p     = __builtin_amdgcn_cvt_pk_fp8_f32(acc[i][2][r], acc[i][3][r], p, true);
      Cb[rowl * 36 + cbase] = (unsigned int)p;
    }
  }
  if (do_e) {
#pragma unroll
    for (int i = 0; i < 4; ++i) {
#pragma unroll
      for (int r = 0; r < 4; ++r) {
        int row = bm + wr0 + i * 16 + quad * 4 + r;
        if (row < M && ln < 8) {
          float* dst = (ln < 4) ? es : ed;
          dst[(size_t)row * nh + (ln & 3)] = acc_e[i][r];
        }
      }
    }
  }
  __syncthreads();

  // ---- epilogue phase B: coalesced C store ----
  {
    const int rT = tid >> 1;          // 0..127
    const int hT = tid & 1;           // col-half 64*hT
    const unsigned int* cp = &Cb[rT * 36 + 16 * hT];
    uint4 d0 = *(const uint4*)(cp + 0);
    uint4 d1 = *(const uint4*)(cp + 4);
    uint4 d2 = *(const uint4*)(cp + 8);
    uint4 d3 = *(const uint4*)(cp + 12);
    int grow = bm + rT;
    if (grow < M) {
      unsigned char* gp = Cout + (size_t)grow * N + bn + 64 * hT;
      uint4 o;
      o.x = bsel(d0, 0); o.y = bsel(d1, 0); o.z = bsel(d2, 0); o.w = bsel(d3, 0);
      *(uint4*)(gp + 0) = o;
      o.x = bsel(d0, 1); o.y = bsel(d1, 1); o.z = bsel(d2, 1); o.w = bsel(d3, 1);
      *(uint4*)(gp + 16) = o;
      o.x = bsel(d0, 2); o.y = bsel(d1, 2); o.z = bsel(d2, 2); o.w = bsel(d3, 2);
      *(uint4*)(gp + 32) = o;
      o.x = bsel(d0, 3); o.y = bsel(d1, 3); o.z = bsel(d2, 3); o.w = bsel(d3, 3);
      *(uint4*)(gp + 48) = o;
    }
  }
}

// ---------------- skinny MFMA GEMM, N=64, split-K, fp32 partials ----------------
__global__ __launch_bounds__(256) void gemm_mfma_n64(
    const unsigned short* __restrict__ A, int lda,
    const unsigned short* __restrict__ BT, int ldb,
    float* __restrict__ Cp, int M, int kchunk)
{
  const int LDT = 72;
  __shared__ unsigned short As[128 * 72];
  __shared__ unsigned short Bs[64 * 72];
  const int tid  = threadIdx.x;
  const int wave = tid >> 6;
  const int lane = tid & 63;
  const int ln   = lane & 15;
  const int quad = lane >> 4;
  const int ks   = blockIdx.x;
  const int bm   = blockIdx.y * 128;
  const int k_beg = ks * kchunk;
  const int k_end = k_beg + kchunk;
  const int arow = tid >> 1;
  const int akb  = (tid & 1) * 32;
  const int brow = tid >> 2;
  const int bkb  = (tid & 3) * 16;

  f32x4 acc[2][4];
  const f32x4 z4 = {0.f, 0.f, 0.f, 0.f};
#pragma unroll
  for (int i = 0; i < 2; ++i)
#pragma unroll
    for (int j = 0; j < 4; ++j) acc[i][j] = z4;

  for (int k0 = k_beg; k0 < k_end; k0 += 64) {
    const unsigned short* ap = A + (size_t)(bm + arow) * lda + k0 + akb;
#pragma unroll
    for (int q = 0; q < 4; ++q)
      *(bf16x8*)(&As[arow * LDT + akb + q * 8]) = *(const bf16x8*)(ap + q * 8);
    const unsigned short* bp = BT + (size_t)brow * ldb + k0 + bkb;
#pragma unroll
    for (int q = 0; q < 2; ++q)
      *(bf16x8*)(&Bs[brow * LDT + bkb + q * 8]) = *(const bf16x8*)(bp + q * 8);
    __syncthreads();
#pragma unroll
    for (int kk = 0; kk < 2; ++kk) {
      bf16x8 af[2], bfv[4];
#pragma unroll
      for (int i = 0; i < 2; ++i)
        af[i] = *(const bf16x8*)(&As[(wave * 32 + i * 16 + ln) * LDT + kk * 32 + quad * 8]);
#pragma unroll
      for (int j = 0; j < 4; ++j)
        bfv[j] = *(const bf16x8*)(&Bs[(j * 16 + ln) * LDT + kk * 32 + quad * 8]);
#pragma unroll
      for (int i = 0; i < 2; ++i)
#pragma unroll
        for (int j = 0; j < 4; ++j)
          acc[i][j] = __builtin_amdgcn_mfma_f32_16x16x32_bf16(af[i], bfv[j], acc[i][j], 0, 0, 0);
    }
    __syncthreads();
  }
#pragma unroll
  for (int i = 0; i < 2; ++i)
#pragma unroll
    for (int r = 0; r < 4; ++r) {
      int row = bm + wave * 32 + i * 16 + quad * 4 + r;
#pragma unroll
      for (int j = 0; j < 4; ++j)
        Cp[((size_t)ks * M + row) * 64 + j * 16 + ln] = acc[i][j][r];
    }
}

// ---------------- fp partial reduce + bias -> bf16 into z cols [512,576) ----------------
__global__ void fp_finish(const float* __restrict__ Cp, int ksplit, int M,
                          const float* __restrict__ bfp,
                          unsigned short* __restrict__ zb)
{
  const int g = blockIdx.x;
  const int j = threadIdx.x;
  float s = bfp[j];
  for (int ks = 0; ks < ksplit; ++ks) s += Cp[((size_t)ks * M + g) * 64 + j];
  zb[(size_t)g * 576 + 512 + j] = f2b_rne(s);
}

// ---------------- mlp partial reduce + bias + relu + fc2 dot -> out ----------------
__global__ void mlp_finish(const float* __restrict__ Cp, int ksplit, int M,
                           const float* __restrict__ bfc1,
                           const float* __restrict__ Wfc2, const float* __restrict__ bfc2,
                           float* __restrict__ out)
{
  const int g = blockIdx.x;
  const int j = threadIdx.x;
  float s = bfc1[j];
  for (int ks = 0; ks < ksplit; ++ks) s += Cp[((size_t)ks * M + g) * 64 + j];
  s = s > 0.f ? s : 0.f;
  float term = s * Wfc2[j];
  for (int off = 32; off; off >>= 1) term += __shfl_down(term, off, 64);
  if (j == 0) out[g] = term + bfc2[0];
}

// ---------------- fused count: edge degrees + graph counts ----------------
__global__ void count_all(const int* __restrict__ ei, int E, int* __restrict__ deg,
                          const int* __restrict__ batch, int NN, int* __restrict__ gcnt,
                          int BE)
{
  int b = blockIdx.x;
  int t = threadIdx.x;
  if (b < BE) {
    int e = b * 256 + t;
    if (e < E) atomicAdd(&deg[ei[E + e]], 1);
  } else {
    int i = (b - BE) * 256 + t;
    if (i < NN) atomicAdd(&gcnt[batch[i]], 1);
  }
}

__global__ void fill_csr(const int* __restrict__ ei, int E, int* __restrict__ cursor,
                         const int* __restrict__ rowptr, int* __restrict__ csr_src)
{
  int e = blockIdx.x * 256 + threadIdx.x;
  if (e < E) {
    int d = ei[E + e];
    int pos = atomicAdd(&cursor[d], 1);
    csr_src[rowptr[d] + pos] = ei[e];
  }
}

// ---------------- fused 3-phase exclusive scans ----------------
__device__ void scan_p1_body(const int* __restrict__ vals, int n, int* __restrict__ bsum,
                             int bb)
{
  __shared__ int red[256];
  int base = bb * 1024;
  int t = threadIdx.x;
  int s = 0;
#pragma unroll
  for (int i = 0; i < 4; ++i) {
    int idx = base + i * 256 + t;
    if (idx < n) s += vals[idx];
  }
  red[t] = s;
  __syncthreads();
  for (int off = 128; off; off >>= 1) {
    if (t < off) red[t] += red[t + off];
    __syncthreads();
  }
  if (t == 0) bsum[bb] = red[0];
}

__global__ void scan2_p1(const int* __restrict__ vA, int nA, int* __restrict__ bsA, int nbA,
                         const int* __restrict__ vB, int nB, int* __restrict__ bsB)
{
  int b = blockIdx.x;
  if (b < nbA) scan_p1_body(vA, nA, bsA, b);
  else         scan_p1_body(vB, nB, bsB, b - nbA);
}

__device__ void scan_p2_body(const int* __restrict__ bsum, int* __restrict__ bpre,
                             int nb, int* __restrict__ rowptr, int n)
{
  __shared__ int tmp[128];
  int t = threadIdx.x;
  int v = (t < nb) ? bsum[t] : 0;
  tmp[t] = v;
  __syncthreads();
  for (int off = 1; off < 128; off <<= 1) {
    int add = (t >= off) ? tmp[t - off] : 0;
    __syncthreads();
    tmp[t] += add;
    __syncthreads();
  }
  if (t < nb) bpre[t] = tmp[t] - v;
  if (t == 127) rowptr[n] = tmp[127];
}

__global__ void scan2_p2(const int* __restrict__ bsA, int* __restrict__ bpA, int nbA,
                         int* __restrict__ rpA, int nA,
                         const int* __restrict__ bsB, int* __restrict__ bpB, int nbB,
                         int* __restrict__ rpB, int nB)
{
  if (blockIdx.x == 0) scan_p2_body(bsA, bpA, nbA, rpA, nA);
  else                 scan_p2_body(bsB, bpB, nbB, rpB, nB);
}

__device__ void scan_p3_body(const int* __restrict__ vals, const int* __restrict__ bpre,
                             int n, int* __restrict__ rowptr, int bb)
{
  __shared__ int tmp[256];
  int t = threadIdx.x;
  int base = bb * 1024 + t * 4;
  int v[4]; int s = 0;
#pragma unroll
  for (int i = 0; i < 4; ++i) {
    int idx = base + i;
    v[i] = (idx < n) ? vals[idx] : 0;
    s += v[i];
  }
  tmp[t] = s;
  __syncthreads();
  for (int off = 1; off < 256; off <<= 1) {
    int add = (t >= off) ? tmp[t - off] : 0;
    __syncthreads();
    tmp[t] += add;
    __syncthreads();
  }
  int run = bpre[bb] + tmp[t] - s;
#pragma unroll
  for (int i = 0; i < 4; ++i) {
    int idx = base + i;
    if (idx < n) rowptr[idx] = run;
    run += v[i];
  }
}

__global__ void scan2_p3(const int* __restrict__ vA, const int* __restrict__ bpA, int nA,
                         int* __restrict__ rpA, int nbA,
                         const int* __restrict__ vB, const int* __restrict__ bpB, int nB,
                         int* __restrict__ rpB)
{
  int b = blockIdx.x;
  if (b < nbA) scan_p3_body(vA, bpA, nA, rpA, b);
  else         scan_p3_body(vB, bpB, nB, rpB, b - nbA);
}

// ---------------- attention weights, one pass: unnormalized w + dinv ----------------
// Unroll-4 MLP: 4 csr_src + 4 es gathers in flight before the exp/store group.
// sum accumulation order preserved (sequential adds).
__global__ void alpha_kernel(const float* __restrict__ es, const float* __restrict__ ed,
                             const int* __restrict__ rowptr, const int* __restrict__ csr_src,
                             float* __restrict__ w_csr, float* __restrict__ wself,
                             float* __restrict__ dinv, int N, int nh)
{
  int idx = blockIdx.x * 256 + threadIdx.x;
  if (idx >= N * nh) return;
  const int dst = idx / nh;
  const int h = idx - dst * nh;
  const float edh = ed[(size_t)dst * nh + h];
  const int beg = rowptr[dst], end = rowptr[dst + 1];
  float sum = 0.f;
  int e = beg;
  for (; e + 3 < end; e += 4) {
    int s0 = csr_src[e], s1 = csr_src[e + 1], s2 = csr_src[e + 2], s3 = csr_src[e + 3];
    float l0 = es[(size_t)s0 * nh + h] + edh;
    float l1 = es[(size_t)s1 * nh + h] + edh;
    float l2 = es[(size_t)s2 * nh + h] + edh;
    float l3 = es[(size_t)s3 * nh + h] + edh;
    l0 = l0 >= 0.f ? l0 : NEG_SLOPE * l0;
    l1 = l1 >= 0.f ? l1 : NEG_SLOPE * l1;
    l2 = l2 >= 0.f ? l2 : NEG_SLOPE * l2;
    l3 = l3 >= 0.f ? l3 : NEG_SLOPE * l3;
    float w0 = expf(l0), w1 = expf(l1), w2 = expf(l2), w3 = expf(l3);
    w_csr[(size_t)e * nh + h] = w0;
    w_csr[(size_t)(e + 1) * nh + h] = w1;
    w_csr[(size_t)(e + 2) * nh + h] = w2;
    w_csr[(size_t)(e + 3) * nh + h] = w3;
    sum += w0; sum += w1; sum += w2; sum += w3;
  }
  for (; e < end; ++e) {
    int s = csr_src[e];
    float l = es[(size_t)s * nh + h] + edh;
    l = l >= 0.f ? l : NEG_SLOPE * l;
    float w = expf(l);
    w_csr[(size_t)e * nh + h] = w;
    sum += w;
  }
  float ls = es[(size_t)dst * nh + h] + edh;
  ls = ls >= 0.f ? ls : NEG_SLOPE * ls;
  float wsl = expf(ls);
  sum += wsl;
  wself[(size_t)dst * nh + h] = wsl;
  dinv[(size_t)dst * nh + h] = 1.0f / sum;
}

// ---------------- conv1 aggregate: fp8 gather + dinv + bias + ELU -> bf16 ----------------
__global__ __launch_bounds__(256) void aggregate_b(
    const unsigned char* __restrict__ h,
    const float* __restrict__ w_csr, const float* __restrict__ wself,
    const float* __restrict__ dinv,
    const int* __restrict__ rowptr, const int* __restrict__ csr_src,
    const float* __restrict__ bias, unsigned short* __restrict__ out,
    int N, int nh, int C)
{
  const int HC = nh * C;                 // 256
  const int CH8 = HC >> 3;               // 32 lanes/dst
  const int dpb = 256 / CH8;             // 8 dsts/block
  const int grp = threadIdx.x / CH8;
  const int lane = threadIdx.x - grp * CH8;
  const int dst = blockIdx.x * dpb + grp;
  if (dst >= N) return;
  const int ch = lane << 3;
  const int head = ch / C;
  const int beg = rowptr[dst], end = rowptr[dst + 1];
  float acc[8] = {0.f, 0.f, 0.f, 0.f, 0.f, 0.f, 0.f, 0.f};
  float hv[8];
  int e = beg;
  for (; e + 1 < end; e += 2) {
    int s0 = csr_src[e], s1 = csr_src[e + 1];
    float a0 = w_csr[(size_t)e * nh + head];
    float a1 = w_csr[(size_t)(e + 1) * nh + head];
    uint2 r0 = *(const uint2*)(h + (size_t)s0 * HC + ch);
    uint2 r1 = *(const uint2*)(h + (size_t)s1 * HC + ch);
    fp8x8_to_f32(r0, hv);
#pragma unroll
    for (int r = 0; r < 8; ++r) acc[r] = fmaf(a0, hv[r], acc[r]);
    fp8x8_to_f32(r1, hv);
#pragma unroll
    for (int r = 0; r < 8; ++r) acc[r] = fmaf(a1, hv[r], acc[r]);
  }
  if (e < end) {
    int s0 = csr_src[e];
    float a0 = w_csr[(size_t)e * nh + head];
    uint2 r0 = *(const uint2*)(h + (size_t)s0 * HC + ch);
    fp8x8_to_f32(r0, hv);
#pragma unroll
    for (int r = 0; r < 8; ++r) acc[r] = fmaf(a0, hv[r], acc[r]);
  }
  {
    float a = wself[(size_t)dst * nh + head];
    uint2 r0 = *(const uint2*)(h + (size_t)dst * HC + ch);
    fp8x8_to_f32(r0, hv);
#pragma unroll
    for (int r = 0; r < 8; ++r) acc[r] = fmaf(a, hv[r], acc[r]);
  }
  const float di = dinv[(size_t)dst * nh + head];
  bf16x8 o;
#pragma unroll
  for (int r = 0; r < 8; ++r) {
    float v = acc[r] * di + bias[ch + r];
    v = v > 0.f ? v : (expf(v) - 1.0f);
    o[r] = (short)f2b_rne(v);
  }
  *(bf16x8*)(out + (size_t)dst * HC + ch) = o;
}

// ---------------- conv2 aggregate + ELU + mean-pool, fp8 gather, one block/graph ----------------
__global__ __launch_bounds__(256) void agg_pool(
    const unsigned char* __restrict__ h,
    const float* __restrict__ w_csr, const float* __restrict__ wself,
    const float* __restrict__ dinv,
    const int* __restrict__ rowptr, const int* __restrict__ csr_src,
    const float* __restrict__ bias, const int* __restrict__ grp,
    unsigned short* __restrict__ zb)
{
  const int g = blockIdx.x;
  const int wave = threadIdx.x >> 6;
  const int lane = threadIdx.x & 63;
  const int ch = lane << 3;
  const int head = lane >> 4;          // ch/128
  const int gbeg = grp[g], gend = grp[g + 1];
  float bch[8];
#pragma unroll
  for (int r = 0; r < 8; ++r) bch[r] = bias[ch + r];
  float pool[8] = {0.f, 0.f, 0.f, 0.f, 0.f, 0.f, 0.f, 0.f};
  float hv[8];

  for (int node = gbeg + wave; node < gend; node += 4) {
    const int beg = rowptr[node], end = rowptr[node + 1];
    float acc[8] = {0.f, 0.f, 0.f, 0.f, 0.f, 0.f, 0.f, 0.f};
    int e = beg;
    for (; e + 1 < end; e += 2) {
      int s0 = csr_src[e], s1 = csr_src[e + 1];
      float a0 = w_csr[(size_t)e * 4 + head];
      float a1 = w_csr[(size_t)(e + 1) * 4 + head];
      uint2 r0 = *(const uint2*)(h + (size_t)s0 * 512 + ch);
      uint2 r1 = *(const uint2*)(h + (size_t)s1 * 512 + ch);
      fp8x8_to_f32(r0, hv);
#pragma unroll
      for (int r = 0; r < 8; ++r) acc[r] = fmaf(a0, hv[r], acc[r]);
      fp8x8_to_f32(r1, hv);
#pragma unroll
      for (int r = 0; r < 8; ++r) acc[r] = fmaf(a1, hv[r], acc[r]);
    }
    if (e < end) {
      int s0 = csr_src[e];
      float a0 = w_csr[(size_t)e * 4 + head];
      uint2 r0 = *(const uint2*)(h + (size_t)s0 * 512 + ch);
      fp8x8_to_f32(r0, hv);
#pragma unroll
      for (int r = 0; r < 8; ++r) acc[r] = fmaf(a0, hv[r], acc[r]);
    }
    {
      float a = wself[(size_t)node * 4 + head];
      uint2 r0 = *(const uint2*)(h + (size_t)node * 512 + ch);
      fp8x8_to_f32(r0, hv);
#pragma unroll
      for (int r = 0; r < 8; ++r) acc[r] = fmaf(a, hv[r], acc[r]);
    }
    const float di = dinv[(size_t)node * 4 + head];
#pragma unroll
    for (int r = 0; r < 8; ++r) {
      float v = acc[r] * di + bch[r];
      v = v > 0.f ? v : (expf(v) - 1.0f);   // ELU
      pool[r] += v;
    }
  }

  __shared__ float red[4][512];
#pragma unroll
  for (int r = 0; r < 8; ++r) red[wave][ch + r] = pool[r];
  __syncthreads();
  const float inv = 1.0f / (float)max(gend - gbeg, 1);
#pragma unroll
  for (int k = 0; k < 2; ++k) {
    int c = threadIdx.x + k * 256;
    float s = (red[0][c] + red[1][c]) + (red[2][c] + red[3][c]);
    zb[(size_t)g * 576 + c] = f2b_rne(s * inv);
  }
}

// ---------------- launcher ----------------
extern "C" void kernel_launch(void* const* d_in, const int* in_sizes, int n_in,
                              void* d_out, int out_size, void* d_ws, size_t ws_size,
                              hipStream_t stream)
{
  const float* x      = (const float*)d_in[0];
  const int*   ei     = (const int*)d_in[1];
  const int*   batch  = (const int*)d_in[2];
  const float* fp     = (const float*)d_in[3];
  const float* W1     = (const float*)d_in[4];
  const float* a_src1 = (const float*)d_in[5];
  const float* a_dst1 = (const float*)d_in[6];
  const float* b1     = (const float*)d_in[7];
  const float* W2     = (const float*)d_in[8];
  const float* a_src2 = (const float*)d_in[9];
  const float* a_dst2 = (const float*)d_in[10];
  const float* b2     = (const float*)d_in[11];
  const float* Wfp    = (const float*)d_in[12];
  const float* bfp    = (const float*)d_in[13];
  const float* Wfc1   = (const float*)d_in[14];
  const float* bfc1   = (const float*)d_in[15];
  const float* Wfc2   = (const float*)d_in[16];
  const float* bfc2   = (const float*)d_in[17];
  float* out = (float*)d_out;

  const int NN = in_sizes[0] / 128;
  const int E  = in_sizes[1] / 2;
  const int G  = in_sizes[3] / 2048;
  const int FIN = 128, H = 4, C1 = 64, C2 = 128;
  const int HC1 = H * C1;   // 256
  const int HC2 = H * C2;   // 512
  const int KFP = in_sizes[3] / G;   // 2048
  const int KZ  = HC2 + 64;          // 576
  const int KS_FP = 16;
  const int KS_Z  = 9;

  // ---- workspace: liverange-overlaid regions ----
  char* base = (char*)d_ws;
  size_t off = 0;
  auto alloc = [&](size_t bytes) {
    char* p = base + off; off += (bytes + 255) & ~(size_t)255; return p;
  };
  // Region A: early xb(bf16)+h1b(fp8); late h2b(fp8)
  size_t xb_sz  = ((size_t)NN * FIN * 2 + 255) & ~(size_t)255;
  size_t h1b_sz = (size_t)NN * HC1;        // fp8: 1 B/elem
  size_t h2b_sz = (size_t)NN * HC2;        // fp8
  size_t rA = xb_sz + h1b_sz; if (h2b_sz > rA) rA = h2b_sz;
  char* RA = alloc(rA);
  unsigned short* xb  = (unsigned short*)RA;
  unsigned char*  h1b = (unsigned char*)(RA + xb_sz);
  unsigned char*  h2b = (unsigned char*)RA;
  // Region B: early fpb+Cp_fp; late agg1b (bf16 — GEMM input)
  size_t fpb_sz  = ((size_t)G * KFP * 2 + 255) & ~(size_t)255;
  size_t cpfp_sz = (size_t)KS_FP * G * 64 * 4;
  size_t agg1_sz = (size_t)NN * HC1 * 2;
  size_t rB = fpb_sz + cpfp_sz; if (agg1_sz > rB) rB = agg1_sz;
  char* RB = alloc(rB);
  unsigned short* fpb   = (unsigned short*)RB;
  float*          Cp_fp = (float*)(RB + fpb_sz);
  unsigned short* agg1b = (unsigned short*)RB;
  // Region C: attn buffers (conv1 then conv2 sequentially)
  float* w1     = (float*)alloc((size_t)E * H * 4);
  float* wself1 = (float*)alloc((size_t)NN * H * 4);
  float* es1    = (float*)alloc((size_t)NN * H * 4);
  float* ed1    = (float*)alloc((size_t)NN * H * 4);
  float* dinv1  = (float*)alloc((size_t)NN * H * 4);
  float* w2 = w1, *wself2 = wself1, *es2 = es1, *ed2 = ed1, *dinv2 = dinv1;
  // Persistent small buffers
  unsigned short* zb    = (unsigned short*)alloc((size_t)G * KZ * 2);
  float*          Cp_z  = (float*)alloc((size_t)KS_Z * G * 64 * 4);
  unsigned short* W1T   = (unsigned short*)alloc((size_t)HC1 * FIN * 2);
  unsigned short* W2T   = (unsigned short*)alloc((size_t)HC2 * HC1 * 2);
  unsigned short* WfpT  = (unsigned short*)alloc((size_t)64 * KFP * 2);
  unsigned short* Wfc1T = (unsigned short*)alloc((size_t)64 * KZ * 2);
  unsigned short* BeT1  = (unsigned short*)alloc((size_t)8 * 128 * 2);
  unsigned short* BeT2  = (unsigned short*)alloc((size_t)8 * 256 * 2);
  // int arena: deg/cursor/gcnt contiguous (single memset covers exactly this span)
  int* iarena   = (int*)alloc(((size_t)2 * NN + G) * 4);
  int* deg      = iarena;
  int* cursor   = iarena + NN;
  int* gcnt     = iarena + 2 * NN;
  int* rowptr_n = (int*)alloc(((size_t)NN + 1) * 4);
  int* rowptr_g = (int*)alloc(((size_t)G + 1) * 4);
  int* csr_src  = (int*)alloc((size_t)E * 4);
  int* bsumA    = (int*)alloc(128 * 4);
  int* bpreA    = (int*)alloc(128 * 4);
  int* bsumB    = (int*)alloc(128 * 4);
  int* bpreB    = (int*)alloc(128 * 4);

  // ---- fused prep ----
  const size_t nx = (size_t)NN * FIN;
  const size_t nf = (size_t)G * KFP;
  const int B0 = (int)((nx + 255) / 256);
  const int B1 = (int)((nf + 255) / 256);
  {
    int nb = B0 + B1 + 128 + 512 + 512 + 144;
    prep_all<<<nb, 256, 0, stream>>>(x, xb, nx, B0, fp, fpb, nf, B1,
                                     W1, W1T, W2, W2T, Wfp, WfpT, Wfc1, Wfc1T);
  }
  prep_e<<<8, 256, 0, stream>>>(W1, a_src1, a_dst1, W2, a_src2, a_dst2, BeT1, BeT2);

  // ---- fingerprint branch ----
  {
    dim3 gg(KS_FP, G / 128);
    gemm_mfma_n64<<<gg, 256, 0, stream>>>(fpb, KFP, WfpT, KFP, Cp_fp, G, KFP / KS_FP);
    fp_finish<<<G, 64, 0, stream>>>(Cp_fp, KS_FP, G, bfp, zb);
  }

  // ---- CSR by dst + graph segment ptrs ----
  hipMemsetAsync(iarena, 0, sizeof(int) * ((size_t)2 * NN + G), stream);
  {
    int BE = (E + 255) / 256;
    int BN = (NN + 255) / 256;
    count_all<<<BE + BN, 256, 0, stream>>>(ei, E, deg, batch, NN, gcnt, BE);
  }
  {
    int nbA = (NN + 1023) / 1024;
    int nbB = (G + 1023) / 1024;
    scan2_p1<<<nbA + nbB, 256, 0, stream>>>(deg, NN, bsumA, nbA, gcnt, G, bsumB);
    scan2_p2<<<2, 128, 0, stream>>>(bsumA, bpreA, nbA, rowptr_n, NN,
                                    bsumB, bpreB, nbB, rowptr_g, G);
    scan2_p3<<<nbA + nbB, 256, 0, stream>>>(deg, bpreA, NN, rowptr_n, nbA,
                                            gcnt, bpreB, G, rowptr_g);
  }
  fill_csr<<<(E + 255) / 256, 256, 0, stream>>>(ei, E, cursor, rowptr_n, csr_src);

  // ---- conv1: GEMM (fp8 h1 + fused e-cols) -> alpha -> aggregate ----
  {
    const int nrow = (NN + 127) / 128;
    gemm_mfma<128><<<nrow * (HC1 / 128), 256, 0, stream>>>(
        xb, W1T, h1b, NN, HC1, BeT1, es1, ed1, H);
  }
  alpha_kernel<<<(NN * H + 255) / 256, 256, 0, stream>>>(es1, ed1, rowptr_n, csr_src,
                                                         w1, wself1, dinv1, NN, H);
  aggregate_b<<<(NN + 7) / 8, 256, 0, stream>>>(h1b, w1, wself1, dinv1, rowptr_n, csr_src,
                                                b1, agg1b, NN, H, C1);

  // ---- conv2: GEMM (fp8 h2 + fused e-cols) -> alpha -> fused aggregate+pool ----
  {
    const int nrow = (NN + 127) / 128;
    gemm_mfma<256><<<nrow * (HC2 / 128), 256, 0, stream>>>(
        agg1b, W2T, h2b, NN, HC2, BeT2, es2, ed2, H);
  }
  alpha_kernel<<<(NN * H + 255) / 256, 256, 0, stream>>>(es2, ed2, rowptr_n, csr_src,
                                                         w2, wself2, dinv2, NN, H);
  agg_pool<<<G, 256, 0, stream>>>(h2b, w2, wself2, dinv2, rowptr_n, csr_src,
                                  b2, rowptr_g, zb);

  // ---- head ----
  {
    dim3 gg(KS_Z, G / 128);
    gemm_mfma_n64<<<gg, 256, 0, stream>>>(zb, KZ, Wfc1T, KZ, Cp_z, G, KZ / KS_Z);
    mlp_finish<<<G, 64, 0, stream>>>(Cp_z, KS_Z, G, bfc1, Wfc2, bfc2, out);
  }
}